// Round 10
// baseline (340.040 us; speedup 1.0000x reference)
//
#include <hip/hip_runtime.h>

// SmartDerivatives: out[b, a*3+dim] = (segment_sum(left * x[b,des]))^2
// Deterministic triu_indices(100,1) scatter; index arrays never read.
//
// R10: R5-R9 pinned at ~55us (42% of achievable HBM) across every staged
// variant. Shared mechanism: stage->barrier->compute with compiler vmcnt(0)
// drains serializing each wave's memory and compute phases. This version:
// R5's proven zero-atomic structure (lane = column j, register col-accums,
// DPP row reductions) + explicit cur/nxt REGISTER double-buffer prefetch
// (row i+8's 8 loads issued before computing row i) and ZERO barriers until
// the single epilogue combine. Single kernel, squares fused in epilogue.

#define N_ATOMS 100
#define D_DESC  4950
#define BATCH   1024
#define NOUT    300
#define NWAVES  8

__device__ __forceinline__ int rowstart(int i) { return (i * (199 - i)) >> 1; }

// one DPP reduce step: v += dpp_shuffled(v), zero-filled OOB
template<int CTRL, int RMASK>
__device__ __forceinline__ float dpp_step(float v) {
    int s = __builtin_amdgcn_update_dpp(0, __float_as_int(v), CTRL, RMASK, 0xf, true);
    return v + __int_as_float(s);
}
// full 64-lane sum; result valid in lane 63. VALU-pipe only.
__device__ __forceinline__ float wave_sum(float v) {
    v = dpp_step<0x111, 0xf>(v);   // row_shr:1
    v = dpp_step<0x112, 0xf>(v);   // row_shr:2
    v = dpp_step<0x114, 0xf>(v);   // row_shr:4
    v = dpp_step<0x118, 0xf>(v);   // row_shr:8
    v = dpp_step<0x142, 0xa>(v);   // row_bcast:15
    v = dpp_step<0x143, 0xc>(v);   // row_bcast:31 -> lane63 = total
    return v;
}

struct Row {
    float2 a01, a23, a45;  float ax;   // half A: j = lane
    float2 b01, b23, b45;  float bx;   // half B: j = 64 + lane
};

__device__ __forceinline__ void load_row(const float* __restrict__ lb,
                                         const float* __restrict__ xb,
                                         int i, int lane, Row& r) {
    const int rs = rowstart(i);
    {   // half A: j = lane; clamped addr for invalid lanes (masked at compute)
        const int j    = lane;
        const int doff = (j > i) ? (j - i - 1) : 0;
        const float* lp = lb + (size_t)(rs + doff) * 6;
        r.a01 = *(const float2*)(lp);
        r.a23 = *(const float2*)(lp + 2);
        r.a45 = *(const float2*)(lp + 4);
        r.ax  = xb[rs + doff];
    }
    {   // half B: j = 64 + lane
        const int j    = 64 + lane;
        const bool v   = (j < N_ATOMS) && (j > i);
        const int doff = v ? (j - i - 1) : 0;
        const float* lp = lb + (size_t)(rs + doff) * 6;
        r.b01 = *(const float2*)(lp);
        r.b23 = *(const float2*)(lp + 2);
        r.b45 = *(const float2*)(lp + 4);
        r.bx  = xb[rs + doff];
    }
}

__global__ __launch_bounds__(512, 8)
void sd_kernel(const float* __restrict__ x,
               const float* __restrict__ left,
               float* __restrict__ out) {
    __shared__ float rowacc[NOUT];          // row (i-part) sums, uniquely written
    __shared__ float part[NWAVES][NOUT];    // per-wave column (j-part) partials
    const int b    = blockIdx.x;
    const int tid  = threadIdx.x;
    const int w    = tid >> 6;
    const int lane = tid & 63;

    if (tid < 3) rowacc[297 + tid] = 0.0f;  // atom 99 has no row part

    const float* __restrict__ xb = x    + (size_t)b * D_DESC;
    const float* __restrict__ lb = left + (size_t)b * D_DESC * 6;

    // lane l owns output columns j=l (a*) and j=64+l (b*, l<36)
    float a0 = 0.f, a1 = 0.f, a2 = 0.f;
    float b0 = 0.f, b1 = 0.f, b2 = 0.f;

    Row cur, nxt;
    if (w < N_ATOMS - 1) load_row(lb, xb, w, lane, cur);

    for (int i = w; i < N_ATOMS - 1; i += NWAVES) {
        // prefetch next row's 8 loads before touching cur
        const int inext = i + NWAVES;
        if (inext < N_ATOMS - 1) load_row(lb, xb, inext, lane, nxt);

        float s0 = 0.f, s1 = 0.f, s2 = 0.f;
        if (i < 63) {   // wave-uniform: half A has valid lanes only for i<63
            const bool v = lane > i;
            const float m = v ? cur.ax : 0.f;
            s0 += cur.a01.x * m;  s1 += cur.a01.y * m;  s2 += cur.a23.x * m;
            a0 += cur.a23.y * m;  a1 += cur.a45.x * m;  a2 += cur.a45.y * m;
        }
        {
            const int  j = 64 + lane;
            const bool v = (j < N_ATOMS) && (j > i);
            const float m = v ? cur.bx : 0.f;
            s0 += cur.b01.x * m;  s1 += cur.b01.y * m;  s2 += cur.b23.x * m;
            b0 += cur.b23.y * m;  b1 += cur.b45.x * m;  b2 += cur.b45.y * m;
        }

        s0 = wave_sum(s0);
        s1 = wave_sum(s1);
        s2 = wave_sum(s2);
        if (lane == 63) {          // row i owned by exactly one wave: plain store
            rowacc[i * 3 + 0] = s0;
            rowacc[i * 3 + 1] = s1;
            rowacc[i * 3 + 2] = s2;
        }
        cur = nxt;                 // garbage on last iter, never consumed
    }

    // per-wave column partials (plain stores, disjoint slices)
    part[w][lane * 3 + 0] = a0;
    part[w][lane * 3 + 1] = a1;
    part[w][lane * 3 + 2] = a2;
    if (lane < N_ATOMS - 64) {
        part[w][(64 + lane) * 3 + 0] = b0;
        part[w][(64 + lane) * 3 + 1] = b1;
        part[w][(64 + lane) * 3 + 2] = b2;
    }
    __syncthreads();               // the ONLY barrier

    // epilogue: total = rowsum + 8 column partials; square; coalesced store
    float* __restrict__ ob = out + (size_t)b * NOUT;
    for (int t = tid; t < NOUT; t += 512) {
        float v = rowacc[t];
        #pragma unroll
        for (int q = 0; q < NWAVES; ++q) v += part[q][t];
        ob[t] = v * v;
    }
}

extern "C" void kernel_launch(void* const* d_in, const int* in_sizes, int n_in,
                              void* d_out, int out_size, void* d_ws, size_t ws_size,
                              hipStream_t stream) {
    const float* x    = (const float*)d_in[0];   // [BATCH, D]
    const float* left = (const float*)d_in[1];   // [BATCH*D*6]
    float* out = (float*)d_out;                  // [BATCH, 300]
    sd_kernel<<<BATCH, 512, 0, stream>>>(x, left, out);
}